// Round 1
// baseline (14279.053 us; speedup 1.0000x reference)
//
#include <hip/hip_runtime.h>
#include <math.h>

#define BB 32
#define LAV 256
#define LCV 256
#define DV 300
#define HV 256
#define G3 768   // 3*H

// ---------- fast math helpers (abs err ~1e-6, well under 3.18e-3 threshold) ----------
static __device__ __forceinline__ float rcp_(float x) { return __builtin_amdgcn_rcpf(x); }
static __device__ __forceinline__ float sigm(float x) { return rcp_(1.f + __expf(-x)); }
static __device__ __forceinline__ float tanh_(float x) { return 1.f - 2.f * rcp_(1.f + __expf(2.f * x)); }

// ---------- weight packing / transposes (run every call; deterministic) ----------
// case0: WT_a  [300][768]  = W_ih_a^T
// case1: WT_cx [300][768]  = W_ih_c[:, :300]^T
// case2: Whha4 [64][768][4]: quad-k pack of W_hh_a^T
// case3: Wq4   [64][256][4]: quad-k pack of Wq (q = h @ Wq)
// case4: Wc1   [128][512][4]: combined [h;ctx] weights for r,z gates (j<512)
// case5: Wc2   [64][512][4]: col<256 = n-gate hidden rows; col>=256 = n-gate ctx rows
__global__ void prep_pack(const float* __restrict__ W_ih_a, const float* __restrict__ W_ih_c,
                          const float* __restrict__ W_hh_a, const float* __restrict__ W_hh_c,
                          const float* __restrict__ Wq,
                          float* __restrict__ WT_a, float* __restrict__ WT_cx,
                          float* __restrict__ Whha4, float* __restrict__ Wq4,
                          float* __restrict__ Wc1, float* __restrict__ Wc2)
{
    int i = blockIdx.x * 256 + threadIdx.x;
    switch (blockIdx.y) {
    case 0: if (i < 300 * 768) { int k = i / 768, n = i % 768; WT_a[i] = W_ih_a[n * 300 + k]; } break;
    case 1: if (i < 300 * 768) { int k = i / 768, n = i % 768; WT_cx[i] = W_ih_c[n * 556 + k]; } break;
    case 2: if (i < 64 * 768 * 4) { int c = i & 3, j = (i >> 2) % 768, k4 = (i >> 2) / 768;
            Whha4[i] = W_hh_a[j * 256 + k4 * 4 + c]; } break;
    case 3: if (i < 64 * 256 * 4) { int c = i & 3, m = (i >> 2) & 255, k4 = (i >> 2) >> 8;
            Wq4[i] = Wq[(k4 * 4 + c) * 256 + m]; } break;
    case 4: if (i < 128 * 512 * 4) { int c = i & 3, j = (i >> 2) & 511, k4 = (i >> 2) >> 9;
            int k = k4 * 4 + c;
            Wc1[i] = (k < 256) ? W_hh_c[j * 256 + k] : W_ih_c[j * 556 + 300 + (k - 256)]; } break;
    case 5: if (i < 64 * 512 * 4) { int c = i & 3, jj = (i >> 2) & 511, k4 = (i >> 2) >> 9;
            int k = k4 * 4 + c;
            Wc2[i] = (jj < 256) ? W_hh_c[(512 + jj) * 256 + k]
                                : W_ih_c[(256 + jj) * 556 + 300 + k]; } break;
    }
}

// ---------- tiled fp32 GEMM: C[M][N] = gather(X)[M][K] @ Wt[K][N] (+bias) ----------
// MODE 0: Cout[m*N+n] = acc + bias[n]            (GI precompute)
// MODE 1: Cout = tanh(acc) scattered to T4[b][h/4][l][h&3]   (keys -> T)
template <int MODE>
__global__ __launch_bounds__(256) void gemm_tile(
    const float* __restrict__ X, const int* __restrict__ gidx, int ldx,
    const float* __restrict__ Wt, int K, int Nn,
    const float* __restrict__ bias, float* __restrict__ Cout)
{
    __shared__ __align__(16) float As[32][68];   // [k][row], padded
    __shared__ __align__(16) float Bs[32][68];   // [k][col], padded
    __shared__ int toks[64];
    int tid = threadIdx.x;
    int m0 = blockIdx.x * 64, n0 = blockIdx.y * 64;
    if (tid < 64) {
        int m = m0 + tid;
        if (gidx) { int t = m >> 5, b = m & 31; toks[tid] = gidx[b * LAV + t]; }
        else toks[tid] = m;
    }
    __syncthreads();
    float acc[4][4] = {};
    int tx = tid & 15, ty = tid >> 4;
    for (int k0 = 0; k0 < K; k0 += 32) {
        { // load A tile (gathered rows), transposed into As[k][r]
            int r = tid >> 2, cc = (tid & 3) * 8;
            const float* src = X + (size_t)toks[r] * ldx + k0 + cc;
            float4 v0 = {0.f,0.f,0.f,0.f}, v1 = {0.f,0.f,0.f,0.f};
            if (k0 + cc + 3 < K) v0 = *(const float4*)src;
            if (k0 + cc + 7 < K) v1 = *(const float4*)(src + 4);
            As[cc+0][r]=v0.x; As[cc+1][r]=v0.y; As[cc+2][r]=v0.z; As[cc+3][r]=v0.w;
            As[cc+4][r]=v1.x; As[cc+5][r]=v1.y; As[cc+6][r]=v1.z; As[cc+7][r]=v1.w;
        }
        { // load B tile
            int kr = tid >> 4, c4 = (tid & 15) * 4;
            #pragma unroll
            for (int p = 0; p < 2; ++p) {
                float4 v = {0.f,0.f,0.f,0.f};
                int kg = k0 + kr + p * 16;
                if (kg < K) v = *(const float4*)(Wt + (size_t)kg * Nn + n0 + c4);
                *(float4*)&Bs[kr + p * 16][c4] = v;
            }
        }
        __syncthreads();
        #pragma unroll 8
        for (int kk = 0; kk < 32; ++kk) {
            float4 a4 = *(const float4*)&As[kk][ty * 4];
            float4 b4 = *(const float4*)&Bs[kk][tx * 4];
            acc[0][0]=fmaf(a4.x,b4.x,acc[0][0]); acc[0][1]=fmaf(a4.x,b4.y,acc[0][1]);
            acc[0][2]=fmaf(a4.x,b4.z,acc[0][2]); acc[0][3]=fmaf(a4.x,b4.w,acc[0][3]);
            acc[1][0]=fmaf(a4.y,b4.x,acc[1][0]); acc[1][1]=fmaf(a4.y,b4.y,acc[1][1]);
            acc[1][2]=fmaf(a4.y,b4.z,acc[1][2]); acc[1][3]=fmaf(a4.y,b4.w,acc[1][3]);
            acc[2][0]=fmaf(a4.z,b4.x,acc[2][0]); acc[2][1]=fmaf(a4.z,b4.y,acc[2][1]);
            acc[2][2]=fmaf(a4.z,b4.z,acc[2][2]); acc[2][3]=fmaf(a4.z,b4.w,acc[2][3]);
            acc[3][0]=fmaf(a4.w,b4.x,acc[3][0]); acc[3][1]=fmaf(a4.w,b4.y,acc[3][1]);
            acc[3][2]=fmaf(a4.w,b4.z,acc[3][2]); acc[3][3]=fmaf(a4.w,b4.w,acc[3][3]);
        }
        __syncthreads();
    }
    if (MODE == 0) {
        float4 bz = *(const float4*)&bias[n0 + tx * 4];
        #pragma unroll
        for (int i = 0; i < 4; ++i) {
            int m = m0 + ty * 4 + i;
            float4 o = { acc[i][0] + bz.x, acc[i][1] + bz.y, acc[i][2] + bz.z, acc[i][3] + bz.w };
            *(float4*)&Cout[(size_t)m * Nn + n0 + tx * 4] = o;
        }
    } else {
        int h4 = (n0 + tx * 4) >> 2;
        #pragma unroll
        for (int i = 0; i < 4; ++i) {
            int m = m0 + ty * 4 + i;
            int b_ = m >> 8, l = m & 255;
            float4 o = { tanh_(acc[i][0]), tanh_(acc[i][1]), tanh_(acc[i][2]), tanh_(acc[i][3]) };
            *(float4*)&Cout[(((size_t)b_ * 64 + h4) * 256 + l) * 4] = o;
        }
    }
}

// ---------- anchor GRU: one WG per batch element ----------
__global__ __launch_bounds__(384) void anchor_rnn(
    const float* __restrict__ GI, const int* __restrict__ lens,
    const float* __restrict__ bhh, const float* __restrict__ Whh4,
    float* __restrict__ AO, float* __restrict__ hid, float* __restrict__ outp)
{
    int bid = blockIdx.x, tid = threadIdx.x;
    __shared__ __align__(16) float hs[256];
    __shared__ float gh[768];
    if (tid < 256) hs[tid] = 0.f;
    float sum = 0.f;
    int len = lens[bid];
    const float4* W4 = (const float4*)Whh4;
    const float4* hs4 = (const float4*)hs;
    __syncthreads();
    for (int t = 0; t < LAV; ++t) {
        { // gh = h @ W_hh_a^T + b_hh_a : 768 outs, 2 per thread
            int j0 = tid, j1 = tid + 384;
            float a0=0.f,a1=0.f,a2=0.f,a3=0.f;
            #pragma unroll 8
            for (int k4 = 0; k4 < 64; ++k4) {
                float4 h4 = hs4[k4];
                float4 w0 = W4[k4 * 768 + j0];
                float4 w1 = W4[k4 * 768 + j1];
                a0=fmaf(w0.x,h4.x,a0); a1=fmaf(w0.y,h4.y,a1); a0=fmaf(w0.z,h4.z,a0); a1=fmaf(w0.w,h4.w,a1);
                a2=fmaf(w1.x,h4.x,a2); a3=fmaf(w1.y,h4.y,a3); a2=fmaf(w1.z,h4.z,a2); a3=fmaf(w1.w,h4.w,a3);
            }
            gh[j0] = a0 + a1 + bhh[j0];
            gh[j1] = a2 + a3 + bhh[j1];
        }
        __syncthreads();
        if (tid < 256) {
            const float* gi = GI + ((size_t)t * BB + bid) * G3;
            float gir = gi[tid], giz = gi[256 + tid], gin = gi[512 + tid];
            float r = sigm(gir + gh[tid]);
            float z = sigm(giz + gh[256 + tid]);
            float n = tanh_(fmaf(r, gh[512 + tid], gin));   // n-gate: r * hidden-part only
            float hk = hs[tid];
            float hn = (1.f - z) * n + z * hk;
            bool valid = (t < len);
            float hnew = valid ? hn : hk;
            hs[tid] = hnew;
            float ov = valid ? hn : 0.f;
            AO[((size_t)bid * LAV + t) * HV + tid] = ov;
            sum += ov;
        }
        __syncthreads();
    }
    if (tid < 256) {
        outp[bid * HV + tid] = sum / (float)len;
        hid[bid * HV + tid] = hs[tid];
    }
}

// ---------- candidate GRU + additive attention: one WG per batch element ----------
__global__ __launch_bounds__(1024) void cand_rnn(
    const float* __restrict__ GI, const int* __restrict__ lens,
    const float* __restrict__ bhh, const float* __restrict__ Wc1,
    const float* __restrict__ Wc2, const float* __restrict__ Wq4,
    const float* __restrict__ v_att, const float* __restrict__ AO,
    const float* __restrict__ T4, const float* __restrict__ hid,
    float* __restrict__ outp)
{
    int bid = blockIdx.x, tid = threadIdx.x;
    __shared__ __align__(16) float hc[512];      // [h ; ctx]
    __shared__ __align__(16) float tqs[256];
    __shared__ __align__(16) float vls[256];
    __shared__ float qp[4][256];                 // q partials, reused as score partials
    __shared__ float attn[256];                  // unnormalized exp
    __shared__ float wred[8];
    __shared__ float ctxp[16][256];
    __shared__ float ghA[512];                   // r,z pre-activations (hidden+ctx, +b_hh)
    __shared__ float ghN[512];                   // [n-hidden(+b_hh) ; n-ctx]
    if (tid < 256) { hc[tid] = hid[bid * HV + tid]; vls[tid] = v_att[tid]; }
    float csum = 0.f;
    int len = lens[bid];
    const float4* hc4 = (const float4*)hc;
    const float4* tq4 = (const float4*)tqs;
    const float4* vl4 = (const float4*)vls;
    const float4* Wq4f = (const float4*)Wq4;
    const float4* Wc1f = (const float4*)Wc1;
    const float4* Wc2f = (const float4*)Wc2;
    const float4* T4f = (const float4*)T4 + (size_t)bid * 64 * 256;
    const float4* AO4 = (const float4*)(AO + (size_t)bid * LAV * HV);
    __syncthreads();
    for (int t = 0; t < LCV; ++t) {
        { // P0: q = h @ Wq, k-split 4-way
            int c = tid >> 8, m = tid & 255;
            float a0 = 0.f, a1 = 0.f;
            #pragma unroll
            for (int k4 = c * 16; k4 < c * 16 + 16; ++k4) {
                float4 h4 = hc4[k4];
                float4 w = Wq4f[k4 * 256 + m];
                a0=fmaf(w.x,h4.x,a0); a1=fmaf(w.y,h4.y,a1); a0=fmaf(w.z,h4.z,a0); a1=fmaf(w.w,h4.w,a1);
            }
            qp[c][m] = a0 + a1;
        }
        __syncthreads();
        if (tid < 256) { // P1: tq = tanh(q)
            float q = qp[0][tid] + qp[1][tid] + qp[2][tid] + qp[3][tid];
            tqs[tid] = tanh_(q);
        }
        __syncthreads();
        { // P2: scores via tanh(k+q) = (T+tq)/(1+T*tq), T precomputed
            int c = tid >> 8, l = tid & 255;
            float acc = 0.f;
            #pragma unroll 4
            for (int h4 = c * 16; h4 < c * 16 + 16; ++h4) {
                float4 Tv = T4f[h4 * 256 + l];
                float4 tv = tq4[h4];
                float4 vv = vl4[h4];
                float d, s;
                d=fmaf(Tv.x,tv.x,1.f); s=Tv.x+tv.x; acc=fmaf(vv.x*s, rcp_(fmaxf(d,1e-30f)), acc);
                d=fmaf(Tv.y,tv.y,1.f); s=Tv.y+tv.y; acc=fmaf(vv.y*s, rcp_(fmaxf(d,1e-30f)), acc);
                d=fmaf(Tv.z,tv.z,1.f); s=Tv.z+tv.z; acc=fmaf(vv.z*s, rcp_(fmaxf(d,1e-30f)), acc);
                d=fmaf(Tv.w,tv.w,1.f); s=Tv.w+tv.w; acc=fmaf(vv.w*s, rcp_(fmaxf(d,1e-30f)), acc);
            }
            qp[c][l] = acc;
        }
        __syncthreads();
        float sv = 0.f;
        if (tid < 256) { // P3: reduce scores, wave max
            sv = qp[0][tid] + qp[1][tid] + qp[2][tid] + qp[3][tid];
            float m = sv;
            #pragma unroll
            for (int o = 1; o < 64; o <<= 1) m = fmaxf(m, __shfl_xor(m, o, 64));
            if ((tid & 63) == 0) wred[tid >> 6] = m;
        }
        __syncthreads();
        if (tid < 256) { // P4: exp + wave sum
            float mx = fmaxf(fmaxf(wred[0], wred[1]), fmaxf(wred[2], wred[3]));
            float e = __expf(sv - mx);
            attn[tid] = e;
            float s = e;
            #pragma unroll
            for (int o = 1; o < 64; o <<= 1) s += __shfl_xor(s, o, 64);
            if ((tid & 63) == 0) wred[4 + (tid >> 6)] = s;
        }
        __syncthreads();
        { // P5: context partials (unnormalized)
            int c2 = tid >> 6, h4 = tid & 63;
            float a0=0.f,a1=0.f,a2=0.f,a3=0.f;
            #pragma unroll 4
            for (int l = c2 * 16; l < c2 * 16 + 16; ++l) {
                float w = attn[l];
                float4 v = AO4[l * 64 + h4];
                a0=fmaf(w,v.x,a0); a1=fmaf(w,v.y,a1); a2=fmaf(w,v.z,a2); a3=fmaf(w,v.w,a3);
            }
            float4 o = { a0, a1, a2, a3 };
            *(float4*)&ctxp[c2][h4 * 4] = o;
        }
        __syncthreads();
        if (tid < 256) { // P6: finalize ctx
            float sumv = wred[4] + wred[5] + wred[6] + wred[7];
            float s = 0.f;
            #pragma unroll
            for (int c2 = 0; c2 < 16; ++c2) s += ctxp[c2][tid];
            hc[256 + tid] = s / sumv;
        }
        __syncthreads();
        // P7: gh1 (r,z over [h;ctx], waves 0-3) || gh2 (n-hidden / n-ctx, waves 4-7)
        if (tid < 256) {
            int j0 = tid, j1 = tid + 256;
            float a0=0.f,a1=0.f,a2=0.f,a3=0.f;
            #pragma unroll 8
            for (int k4 = 0; k4 < 128; ++k4) {
                float4 x4 = hc4[k4];
                float4 w0 = Wc1f[k4 * 512 + j0];
                float4 w1 = Wc1f[k4 * 512 + j1];
                a0=fmaf(w0.x,x4.x,a0); a1=fmaf(w0.y,x4.y,a1); a0=fmaf(w0.z,x4.z,a0); a1=fmaf(w0.w,x4.w,a1);
                a2=fmaf(w1.x,x4.x,a2); a3=fmaf(w1.y,x4.y,a3); a2=fmaf(w1.z,x4.z,a2); a3=fmaf(w1.w,x4.w,a3);
            }
            ghA[j0] = a0 + a1 + bhh[j0];
            ghA[j1] = a2 + a3 + bhh[j1];
        } else if (tid < 512) {
            int jj = tid - 256;
            float a0=0.f,a1=0.f,a2=0.f,a3=0.f;
            #pragma unroll 8
            for (int k4 = 0; k4 < 64; ++k4) {
                float4 xh = hc4[k4];
                float4 xc = hc4[64 + k4];
                float4 w0 = Wc2f[k4 * 512 + jj];
                float4 w1 = Wc2f[k4 * 512 + jj + 256];
                a0=fmaf(w0.x,xh.x,a0); a1=fmaf(w0.y,xh.y,a1); a0=fmaf(w0.z,xh.z,a0); a1=fmaf(w0.w,xh.w,a1);
                a2=fmaf(w1.x,xc.x,a2); a3=fmaf(w1.y,xc.y,a3); a2=fmaf(w1.z,xc.z,a2); a3=fmaf(w1.w,xc.w,a3);
            }
            ghN[jj] = a0 + a1 + bhh[512 + jj];   // hidden part incl b_hh_n
            ghN[256 + jj] = a2 + a3;             // ctx part (bias already in GI via b_ih)
        }
        __syncthreads();
        if (tid < 256) { // P8: elementwise GRU + length mask
            const float* gi = GI + ((size_t)t * BB + bid) * G3;
            float gir = gi[tid], giz = gi[256 + tid], gin = gi[512 + tid];
            float r = sigm(gir + ghA[tid]);
            float z = sigm(giz + ghA[256 + tid]);
            float n = tanh_(fmaf(r, ghN[tid], gin + ghN[256 + tid]));
            float hk = hc[tid];
            float hn = (1.f - z) * n + z * hk;
            float hnew = (len < t) ? hk : hn;    // strict '<' per reference
            hc[tid] = hnew;
            if (t < len) csum += hnew;
        }
        __syncthreads();
    }
    if (tid < 256) outp[8192 + bid * HV + tid] = csum / (float)len;
}

extern "C" void kernel_launch(void* const* d_in, const int* in_sizes, int n_in,
                              void* d_out, int out_size, void* d_ws, size_t ws_size,
                              hipStream_t stream) {
    const int* anchor_input     = (const int*)d_in[0];
    const int* anchor_length    = (const int*)d_in[1];
    const int* candidate_input  = (const int*)d_in[2];
    const int* candidate_length = (const int*)d_in[3];
    const float* emb    = (const float*)d_in[5];
    const float* W_ih_a = (const float*)d_in[6];
    const float* W_hh_a = (const float*)d_in[7];
    const float* b_ih_a = (const float*)d_in[8];
    const float* b_hh_a = (const float*)d_in[9];
    const float* W_ih_c = (const float*)d_in[10];
    const float* W_hh_c = (const float*)d_in[11];
    const float* b_ih_c = (const float*)d_in[12];
    const float* b_hh_c = (const float*)d_in[13];
    const float* Wq     = (const float*)d_in[14];
    const float* Wk     = (const float*)d_in[15];
    const float* v_att  = (const float*)d_in[16];
    float* out = (float*)d_out;

    // workspace layout (floats); total ~17.9M floats = ~72 MB
    float* ws = (float*)d_ws;
    size_t off = 0;
    float* GI_a  = ws + off; off += (size_t)LAV * BB * G3;    // 6291456
    float* GI_c  = ws + off; off += (size_t)LCV * BB * G3;    // 6291456
    float* AO    = ws + off; off += (size_t)BB * LAV * HV;    // 2097152
    float* T4    = ws + off; off += (size_t)BB * 64 * 256 * 4;// 2097152
    float* hid   = ws + off; off += (size_t)BB * HV;          // 8192
    float* WT_a  = ws + off; off += 300 * 768;
    float* WT_cx = ws + off; off += 300 * 768;
    float* Whha4 = ws + off; off += 64 * 768 * 4;
    float* Wq4   = ws + off; off += 64 * 256 * 4;
    float* Wc1   = ws + off; off += 128 * 512 * 4;
    float* Wc2   = ws + off; off += 64 * 512 * 4;

    prep_pack<<<dim3(1024, 6), 256, 0, stream>>>(W_ih_a, W_ih_c, W_hh_a, W_hh_c, Wq,
                                                 WT_a, WT_cx, Whha4, Wq4, Wc1, Wc2);
    // GI_a = emb[anchor] @ W_ih_a^T + b_ih_a   (rows ordered [t][b])
    gemm_tile<0><<<dim3(128, 12), 256, 0, stream>>>(emb, anchor_input, DV, WT_a, DV, G3, b_ih_a, GI_a);
    gemm_tile<0><<<dim3(128, 12), 256, 0, stream>>>(emb, candidate_input, DV, WT_cx, DV, G3, b_ih_c, GI_c);
    anchor_rnn<<<32, 384, 0, stream>>>(GI_a, anchor_length, b_hh_a, Whha4, AO, hid, out);
    // T = tanh(AO @ Wk), packed [b][h/4][l][4]
    gemm_tile<1><<<dim3(128, 4), 256, 0, stream>>>(AO, nullptr, HV, Wk, HV, HV, nullptr, T4);
    cand_rnn<<<32, 1024, 0, stream>>>(GI_c, candidate_length, b_hh_c, Wc1, Wc2, Wq4,
                                      v_att, AO, T4, hid, out);
}